// Round 8
// baseline (55.373 us; speedup 1.0000x reference)
//
#include <hip/hip_runtime.h>
#include <math.h>

#define T_DIM 512
#define B_DIM 64
#define D_DIM 256
#define F_DIM 256
#define ALPHA 0.2f
#define L2E 1.44269504089f
#define NEGL -1.0e38f

// workspace layout (floats). Every slot consumed is written the same call.
#define U_OFF 0
#define V_OFF 256
#define P_OFF 512
#define Q_OFF (P_OFF + T_DIM * B_DIM)
#define GG_OFF (Q_OFF + T_DIM * B_DIM)             // gg[3][B][T]

// ---------- Node 1: u = W@a1, v = W@a2. 64 blocks x 256 thr ----------
__global__ __launch_bounds__(256) void g_uv(const float* __restrict__ W,
                                            const float* __restrict__ a1,
                                            const float* __restrict__ a2,
                                            float* __restrict__ ws) {
    int tid = threadIdx.x;
    int wave = tid >> 6, lane = tid & 63;
    int d = blockIdx.x * 4 + wave;
    float4 wv = ((const float4*)(W + (size_t)d * F_DIM))[lane];
    float4 a1v = ((const float4*)a1)[lane];
    float4 a2v = ((const float4*)a2)[lane];
    float p = wv.x * a1v.x + wv.y * a1v.y + wv.z * a1v.z + wv.w * a1v.w;
    float q = wv.x * a2v.x + wv.y * a2v.y + wv.z * a2v.z + wv.w * a2v.w;
    for (int off = 32; off > 0; off >>= 1) {
        p += __shfl_down(p, off);
        q += __shfl_down(q, off);
    }
    if (lane == 0) {
        ws[U_OFF + d] = p;
        ws[V_OFF + d] = q;
    }
}

// ---------- Node 2: p,q dot products. 512 blocks x 512 thr ----------
// Loads for all 8 rows issued BEFORE any reduce -> 8 KB in flight per wave.
__global__ __launch_bounds__(512) void g_pq(const float* __restrict__ x,
                                            const int* __restrict__ turns,
                                            float* __restrict__ ws) {
    __shared__ float su[D_DIM], sv[D_DIM];
    int tid = threadIdx.x;
    if (tid < 64) ((float4*)su)[tid] = ((const float4*)(ws + U_OFF))[tid];
    else if (tid < 128) ((float4*)sv)[tid - 64] = ((const float4*)(ws + V_OFF))[tid - 64];
    __syncthreads();
    int lane = tid & 63;
    int gw = blockIdx.x * 8 + (tid >> 6);  // [0, 4096)
    int b = gw & 63;
    int tbase = gw >> 6;                   // [0, 64)
    int tn = turns[b];
    float4 uv = ((const float4*)su)[lane];
    float4 vv = ((const float4*)sv)[lane];
    float4 xv[8];
#pragma unroll
    for (int k = 0; k < 8; ++k) {
        int t = tbase + k * 64;
        if (t <= tn)                       // wave-uniform
            xv[k] = ((const float4*)x)[((size_t)t * B_DIM + b) * (D_DIM / 4) + lane];
    }
#pragma unroll
    for (int k = 0; k < 8; ++k) {
        int t = tbase + k * 64;
        if (t <= tn) {
            float pp = xv[k].x * uv.x + xv[k].y * uv.y + xv[k].z * uv.z + xv[k].w * uv.w;
            float qq = xv[k].x * vv.x + xv[k].y * vv.y + xv[k].z * vv.z + xv[k].w * vv.w;
            for (int off = 32; off > 0; off >>= 1) {
                pp += __shfl_down(pp, off);
                qq += __shfl_down(qq, off);
            }
            if (lane == 0) {
                ws[P_OFF + b * T_DIM + t] = pp;
                ws[Q_OFF + b * T_DIM + t] = qq;
            }
        }
    }
}

// ---------- Node 3: fused attention row+col per (b,w); also zeroes d_out ----------
// 192 blocks x 512 threads. GG written unconditionally (no pre-zero needed).
__global__ __launch_bounds__(512) void g_attn(const int* __restrict__ turns,
                                              float* __restrict__ ws,
                                              float* __restrict__ out) {
    int bi = blockIdx.x, tid = threadIdx.x;
    if (bi < 32) out[bi * 512 + tid] = 0.f;   // zero d_out for Node 4 atomics
    int b = bi / 3, w = bi % 3 + 1;
    int tn = turns[b];
    int cnt = tn - w + 2;
    if (cnt > T_DIM) cnt = T_DIM;
    float* GG = ws + GG_OFF + ((w - 1) * B_DIM + b) * T_DIM;
    if (cnt <= 0) {                        // block-uniform
        GG[tid] = 0.f;
        return;
    }
    __shared__ float sp[T_DIM], sq[T_DIM], f2L[T_DIM], red[8];
    __shared__ float2 fc[T_DIM];
    if (tid < 128) {
        ((float4*)sp)[tid] = ((const float4*)(ws + P_OFF + b * T_DIM))[tid];
        ((float4*)sq)[tid] = ((const float4*)(ws + Q_OFF + b * T_DIM))[tid];
    }
    __syncthreads();
    float scale = L2E / (float)w;
    int j = tid;
    float vj;
    if (j < cnt) {
        float a = sq[j];
        if (w > 1) a += sq[j + 1];         // j+w-1 <= tn <= 511, g_pq-written
        if (w > 2) a += sq[j + 2];
        vj = a * scale;
    } else {
        vj = NEGL;
    }
    f2L[j] = vj;
    float m = vj;
    for (int off = 32; off > 0; off >>= 1) m = fmaxf(m, __shfl_down(m, off));
    if ((tid & 63) == 0) red[tid >> 6] = m;
    __syncthreads();                       // covers f2L + red
    float M = red[0];
#pragma unroll
    for (int i2 = 1; i2 < 8; ++i2) M = fmaxf(M, red[i2]);
    if (j < cnt) {
        float a = sp[j];
        if (w > 1) a += sp[j + 1];
        if (w > 2) a += sp[j + 2];
        float f1 = a * scale;
        float s0 = f1 + M;
        float mrow = fmaxf(s0, ALPHA * s0);  // analytic row max (lrelu monotone)
        float r = 0.f;
        for (int jj = 0; jj < cnt; ++jj) {
            float s = f1 + f2L[jj];
            s = fmaxf(s, ALPHA * s);
            r += __builtin_amdgcn_exp2f(s - mrow);
        }
        fc[j] = make_float2(f1, mrow + __builtin_amdgcn_logf(r));  // log2 domain
    }
    __syncthreads();
    float acc = 0.f;
    if (j < cnt) {
        for (int i = 0; i < cnt; ++i) {
            float2 t2 = fc[i];
            float s = t2.x + vj;
            s = fmaxf(s, ALPHA * s);
            acc += __builtin_amdgcn_exp2f(s - t2.y);
        }
        acc /= (float)cnt;
    }
    GG[j] = (j < cnt) ? acc : 0.f;
}

// ---------- Node 4: fused Z + GEMV -> atomicAdd out ----------
// 256 blocks (64 b x 4 chunks of 128 t) x 512 threads.
__global__ __launch_bounds__(512) void g_zout(const float* __restrict__ x,
                                              const int* __restrict__ turns,
                                              const float* __restrict__ W,
                                              const float* __restrict__ ws,
                                              float* __restrict__ out) {
    int b = blockIdx.x >> 2;
    int chunk = blockIdx.x & 3;
    int tn = turns[b];
    int t0 = chunk * 128;
    if (t0 > tn) return;                   // zero contribution (block-uniform)
    int tid = threadIdx.x;
    __shared__ float Cs[128];
    __shared__ float4 zp[512];
    __shared__ float Zs[D_DIM];
    __shared__ float ored[512];
    if (tid < 128) {
        int t = t0 + tid;
        const float* G1 = ws + GG_OFF + (0 * B_DIM + b) * T_DIM;
        const float* G2 = ws + GG_OFF + (1 * B_DIM + b) * T_DIM;
        const float* G3 = ws + GG_OFF + (2 * B_DIM + b) * T_DIM;
        // GG is zero beyond each window's cnt -> C[t]=0 for t>tn automatically.
        float g2 = G2[t] + (t >= 1 ? G2[t - 1] : 0.f);
        float g3 = G3[t] + (t >= 1 ? G3[t - 1] : 0.f) + (t >= 2 ? G3[t - 2] : 0.f);
        float vws = 1.f + (tn >= 1 ? 1.f : 0.f) + (tn >= 2 ? 1.f : 0.f);
        Cs[tid] = (G1[t] + 0.5f * g2 + (1.0f / 3.0f) * g3) / vws;
    }
    __syncthreads();
    int wave = tid >> 6, lane = tid & 63;
    float4 z = make_float4(0.f, 0.f, 0.f, 0.f);
    {
        int tg = t0 + wave * 16;
        size_t base = ((size_t)tg * B_DIM + b) * (D_DIM / 4) + lane;
#pragma unroll 8
        for (int tt = 0; tt < 16; ++tt) {
            float c = Cs[wave * 16 + tt];
            float4 xv = ((const float4*)x)[base + (size_t)tt * (B_DIM * D_DIM / 4)];
            z.x += c * xv.x; z.y += c * xv.y; z.z += c * xv.z; z.w += c * xv.w;
        }
    }
    zp[tid] = z;
    __syncthreads();
    if (tid < 64) {
        float4 a = zp[tid];
#pragma unroll
        for (int k = 1; k < 8; ++k) {
            float4 bb = zp[k * 64 + tid];
            a.x += bb.x; a.y += bb.y; a.z += bb.z; a.w += bb.w;
        }
        ((float4*)Zs)[tid] = a;
    }
    __syncthreads();
    int f = tid & 255, dh = tid >> 8;
    float acc = 0.f;
#pragma unroll 8
    for (int dd = dh * 128; dd < dh * 128 + 128; ++dd)
        acc += Zs[dd] * W[(size_t)dd * F_DIM + f];
    ored[tid] = acc;
    __syncthreads();
    if (tid < 256)
        atomicAdd(&out[b * F_DIM + tid], ored[tid] + ored[tid + 256]);
}

extern "C" void kernel_launch(void* const* d_in, const int* in_sizes, int n_in,
                              void* d_out, int out_size, void* d_ws, size_t ws_size,
                              hipStream_t stream) {
    const float* x = (const float*)d_in[0];     // (T,B,D) fp32
    const int* turns = (const int*)d_in[1];     // (B,) int32
    const float* W = (const float*)d_in[2];     // (D,F)
    const float* a1 = (const float*)d_in[3];    // (F,)
    const float* a2 = (const float*)d_in[4];    // (F,)
    float* out = (float*)d_out;                 // (B,F)
    float* ws = (float*)d_ws;

    g_uv<<<B_DIM, 256, 0, stream>>>(W, a1, a2, ws);
    g_pq<<<512, 512, 0, stream>>>(x, turns, ws);
    g_attn<<<B_DIM * 3, 512, 0, stream>>>(turns, ws, out);
    g_zout<<<B_DIM * 4, 512, 0, stream>>>(x, turns, W, ws, out);
}